// Round 7
// baseline (40.455 us; speedup 1.0000x reference)
//
#include <hip/hip_runtime.h>
#include <math.h>

#define N_MC 256
#define CB 512                 // threads per block (8 waves)
#define MPB 256                // m's per block
#define MAIN_BLOCKS 1024       // MPB * MAIN_BLOCKS == 262144 == M
#define NSLICE 32              // n's per wave (8 waves * 32 = 256)

constexpr float  WF        = 2.5f;
constexpr float  LOG2PI_F  = 1.8378770664093453f;   // log(2*pi)
constexpr float  L2E       = 1.4426950408889634f;   // log2(e)
constexpr float  LN2_F     = 0.6931471805599453f;
constexpr float  PI_F      = 3.14159265358979323846f;
constexpr float  GAMMA_1_5 = 0.8862269254527580f;   // Gamma(1.5)
constexpr float  ERFW_C    = 0.98758066934f;        // erf(2.5/sqrt(2))
constexpr float  GMIN_C    = 0.04393693362f;        // exp(-2.5^2/2)
constexpr double FXSCALE   = 274877906944.0;        // 2^38
constexpr double FXINV     = 1.0 / 274877906944.0;

__device__ __forceinline__ float fexp2(float x) { return __builtin_amdgcn_exp2f(x); }
__device__ __forceinline__ float flog2(float x) { return __builtin_amdgcn_logf(x); }

#define PAIR4(Pj, Tj, Bj)                                            \
    a0 += fexp2(fmaf(Tj, x0, fmaf(Bj, y0, d0)) + Pj);                \
    a1 += fexp2(fmaf(Tj, x1, fmaf(Bj, y1, d1)) + Pj);                \
    a2 += fexp2(fmaf(Tj, x2, fmaf(Bj, y2, d2)) + Pj);                \
    a3 += fexp2(fmaf(Tj, x3, fmaf(Bj, y3, d3)) + Pj);

__global__ __launch_bounds__(CB, 8) void fused_kernel(
        const float* __restrict__ x_g, const float* __restrict__ y_g,
        const float* __restrict__ k_u,
        const float* p_sb, const float* p_sn,
        const float* p_I1, const float* p_I2,
        const float* w1, const float* w2, const float* w12,
        unsigned long long* __restrict__ accum,
        unsigned int* __restrict__ counter,
        float* __restrict__ out, int Mv) {

    __shared__ float  sPp[N_MC], sT[N_MC], sB[N_MC];
    __shared__ float4 srec[MPB];
    __shared__ float  part[8][MPB];
    __shared__ double sred[4];

    int tid  = threadIdx.x;
    int wv   = tid >> 6;
    int lane = tid & 63;
    int mb   = blockIdx.x * MPB;

    // ---- shared scalar setup (all threads; cheap) ----
    float sb = *p_sb, sn = *p_sn, I1 = *p_I1, I2 = *p_I2;
    float sn2 = sn * sn, inv_sn2 = 1.0f / sn2, c2n = 0.5f * inv_sn2;
    float dI = I2 - I1;
    float I_diff = dI * ERFW_C;
    float I_min  = I1 + 0.5f * dI * (1.0f - ERFW_C);
    float A    = dI * rsqrtf(2.0f * PI_F * sb * sb);
    float beta = 2.0f * A * inv_sn2;
    float nC2  = -c2n * L2E;
    float ln_sn = flog2(sn) * LN2_F;
    float CONST0 = -logf(2.0f * WF * dI) - logf(A) - logf(sn) + 0.5f * LN2_F;

    float rr0 = *w1, rr1 = *w2, rr2 = *w12;
    float rm = fmaxf(rr0, fmaxf(rr1, rr2));
    float lse_r = rm + LN2_F * flog2(fexp2((rr0 - rm) * L2E)
                 + fexp2((rr1 - rm) * L2E) + fexp2((rr2 - rm) * L2E));
    float lw0 = rr0 - lse_r, lw1 = rr1 - lse_r, lw2 = rr2 - lse_r;
    float base12 = flog2(I_diff) * LN2_F - 8.0f * LN2_F;
    float Qc = -ln_sn - 0.5f * LOG2PI_F;
    float K  = LN2_F - flog2(GAMMA_1_5) * LN2_F - 4.0f * ln_sn - 0.5f * LOG2PI_F;

    if (tid < N_MC) {
        // ---- per-n constants (log2 domain): s = Pp + T*x + B*y + nC2*x^2 ----
        float tx = k_u[tid] * I_diff + I_min;
        float u  = 2.0f * (tx - I1) / dI - 1.0f;
        float ei = erfinvf(u);
        float e2 = ei * ei;
        float lptx = -logf(2.0f * WF * dI) + 0.5f * LOG2PI_F + e2;
        float G = A * expf(-e2);
        float b = 2.0f * G / sn2;       // z = b*y
        float P = lptx - 0.5f * logf(G) - 0.5f * logf(b) - G * G / sn2
                - 2.0f * logf(sn) + 0.5f * logf(2.0f / PI_F);
        sPp[tid] = (P - c2n * tx * tx) * L2E;
        sT[tid]  = (tx * inv_sn2) * L2E;
        sB[tid]  = b * L2E;
    } else {
        // ---- per-m record {x, y, D2, Cl2} for mi = tid-256 ----
        int mi = tid - N_MC;
        int m  = mb + mi;
        float4 o;
        if (m < Mv) {
            float xv = x_g[m], yv = y_g[m];
            // analytic upper bound C on max_n (P + b*y): unimodal in g
            float disc = fmaf(yv, yv, -4.0f * sn2);
            float root = sqrtf(fmaxf(disc, 0.0f));
            float gs = (yv + root) / (2.0f * A);
            gs = fminf(fmaxf(gs, GMIN_C), 1.0f);
            float Ag = A * gs;
            float Cnn = CONST0 - 2.0f * flog2(gs) * LN2_F - Ag * Ag * inv_sn2
                      + beta * gs * yv;
            float Cl2 = fmaf(Cnn, L2E, 2.0f);         // +2 bits safety margin
            float D2  = fmaf(nC2 * xv, xv, -Cl2);     // nC2*x^2 - C
            o = make_float4(xv, yv, D2, Cl2);
        } else {
            o = make_float4(0.5f, 0.5f, -20000.0f, 0.0f);
        }
        srec[mi] = o;
    }
    __syncthreads();

    // ---- each thread: 4 m's from LDS ----
    float4 r0v = srec[lane];
    float4 r1v = srec[64 + lane];
    float4 r2v = srec[128 + lane];
    float4 r3v = srec[192 + lane];
    float x0 = r0v.x, y0 = r0v.y, d0 = r0v.z;
    float x1 = r1v.x, y1 = r1v.y, d1 = r1v.z;
    float x2 = r2v.x, y2 = r2v.y, d2 = r2v.z;
    float x3 = r3v.x, y3 = r3v.y, d3 = r3v.z;

    const float4* P4 = (const float4*)sPp;
    const float4* T4 = (const float4*)sT;
    const float4* B4 = (const float4*)sB;
    int g0 = wv * (NSLICE / 4);

    float a0 = 0.0f, a1 = 0.0f, a2 = 0.0f, a3 = 0.0f;
#pragma unroll 2
    for (int g = 0; g < NSLICE / 4; ++g) {
        float4 P = P4[g0 + g];
        float4 T = T4[g0 + g];
        float4 B = B4[g0 + g];
        PAIR4(P.x, T.x, B.x)
        PAIR4(P.y, T.y, B.y)
        PAIR4(P.z, T.z, B.z)
        PAIR4(P.w, T.w, B.w)
    }

    part[wv][lane]       = a0;
    part[wv][lane + 64]  = a1;
    part[wv][lane + 128] = a2;
    part[wv][lane + 192] = a3;
    __syncthreads();

    // ---- epilogue: mixture LSE per m (threads 0..255), wave butterfly ----
    if (tid < MPB) {
        int mi = tid;
        float sm = 0.0f;
#pragma unroll
        for (int w = 0; w < 8; ++w) sm += part[w][mi];
        float4 rr = srec[mi];
        double lpd = 0.0;
        if (mb + mi < Mv) {
            float xv = rr.x, yv = rr.y, Cl2 = rr.w;
            float ly  = flog2(yv) * LN2_F;
            float y2s = yv * yv * inv_sn2;
            float lp12 = base12 + ly - y2s + Qc + LN2_F * (Cl2 + flog2(sm));
            float e1 = xv - I1, e2v = xv - I2;
            float base_i = K + 2.0f * ly - y2s;
            float lp1 = base_i - c2n * e1 * e1;
            float lp2 = base_i - c2n * e2v * e2v;
            float b0 = lw0 + lp1, b1 = lw1 + lp2, b2 = lw2 + lp12;
            float mm = fmaxf(b0, fmaxf(b1, b2));
            float lp = mm + LN2_F * flog2(fexp2((b0 - mm) * L2E)
                      + fexp2((b1 - mm) * L2E) + fexp2((b2 - mm) * L2E));
            lpd = (double)lp;
        }
#pragma unroll
        for (int o = 32; o > 0; o >>= 1) lpd += __shfl_xor(lpd, o, 64);
        if (lane == 0) sred[wv] = lpd;
    }
    __syncthreads();

    // ---- deterministic fixed-point atomic accumulate + last-block finish ----
    if (tid == 0) {
        double blk = (sred[0] + sred[1]) + (sred[2] + sred[3]);
        long long q = (long long)(blk * FXSCALE);
        atomicAdd(accum, (unsigned long long)q);
        __threadfence();
        unsigned int old = atomicAdd(counter, 1u);
        if (old == (unsigned int)(gridDim.x - 1)) {
            __threadfence();
            unsigned long long v = atomicAdd(accum, 0ull);
            out[0] = (float)(-((double)(long long)v) * FXINV);
        }
    }
}

extern "C" void kernel_launch(void* const* d_in, const int* in_sizes, int n_in,
                              void* d_out, int out_size, void* d_ws, size_t ws_size,
                              hipStream_t stream) {
    const float* x   = (const float*)d_in[0];
    const float* y   = (const float*)d_in[1];
    const float* k_u = (const float*)d_in[2];
    const float* sb  = (const float*)d_in[3];
    const float* sn  = (const float*)d_in[4];
    const float* I1  = (const float*)d_in[5];
    const float* I2  = (const float*)d_in[6];
    const float* w1  = (const float*)d_in[7];
    const float* w2  = (const float*)d_in[8];
    const float* w12 = (const float*)d_in[9];
    int Mv = in_sizes[0];

    unsigned long long* accum   = (unsigned long long*)d_ws;
    unsigned int*       counter = (unsigned int*)((char*)d_ws + 8);

    hipMemsetAsync(d_ws, 0, 16, stream);
    fused_kernel<<<MAIN_BLOCKS, CB, 0, stream>>>(x, y, k_u, sb, sn, I1, I2,
                                                 w1, w2, w12, accum, counter,
                                                 (float*)d_out, Mv);
}

// Round 8
// 20.416 us; speedup vs baseline: 1.9815x; 1.9815x over previous
//
#include <hip/hip_runtime.h>
#include <math.h>

#define N_MC 256
#define CB 512                 // threads per block (8 waves)
#define MPB 256                // m's per block
#define MAIN_BLOCKS 1024       // MPB * MAIN_BLOCKS == 262144 == M
#define NSLICE 32              // n's per wave (8 waves * 32 = 256)

constexpr float  WF        = 2.5f;
constexpr float  LOG2PI_F  = 1.8378770664093453f;   // log(2*pi)
constexpr float  L2E       = 1.4426950408889634f;   // log2(e)
constexpr float  LN2_F     = 0.6931471805599453f;
constexpr float  PI_F      = 3.14159265358979323846f;
constexpr float  GAMMA_1_5 = 0.8862269254527580f;   // Gamma(1.5)
constexpr float  ERFW_C    = 0.98758066934f;        // erf(2.5/sqrt(2))
constexpr float  GMIN_C    = 0.04393693362f;        // exp(-2.5^2/2)

typedef float v2f __attribute__((ext_vector_type(2)));

__device__ __forceinline__ float fexp2(float x) { return __builtin_amdgcn_exp2f(x); }
__device__ __forceinline__ float flog2(float x) { return __builtin_amdgcn_logf(x); }
__device__ __forceinline__ v2f  splat(float v) { return (v2f){v, v}; }

// per 2-m group: s = pk_fma(T, x, pk_fma(B, y, d)) + P ; acc += {exp2(s.x), exp2(s.y)}
#define PAIRV(Pj, Tj, Bj)                                                     \
    {                                                                         \
        v2f s01 = __builtin_elementwise_fma(splat(Tj), x01,                   \
                   __builtin_elementwise_fma(splat(Bj), y01, d01))            \
                  + splat(Pj);                                                \
        v2f s23 = __builtin_elementwise_fma(splat(Tj), x23,                   \
                   __builtin_elementwise_fma(splat(Bj), y23, d23))            \
                  + splat(Pj);                                                \
        v2f e01, e23;                                                         \
        e01.x = fexp2(s01.x); e01.y = fexp2(s01.y);                           \
        e23.x = fexp2(s23.x); e23.y = fexp2(s23.y);                           \
        a01 += e01; a23 += e23;                                               \
    }

__global__ __launch_bounds__(CB, 8) void fused_kernel(
        const float* __restrict__ x_g, const float* __restrict__ y_g,
        const float* __restrict__ k_u,
        const float* p_sb, const float* p_sn,
        const float* p_I1, const float* p_I2,
        const float* w1, const float* w2, const float* w12,
        double* __restrict__ partials, int Mv) {

    __shared__ float  sPp[N_MC], sT[N_MC], sB[N_MC];
    __shared__ float4 srec[MPB];
    __shared__ float  part[8][MPB];
    __shared__ double sred[4];

    int tid  = threadIdx.x;
    int wv   = tid >> 6;
    int lane = tid & 63;
    int mb   = blockIdx.x * MPB;

    // ---- shared scalar setup (all threads; cheap) ----
    float sb = *p_sb, sn = *p_sn, I1 = *p_I1, I2 = *p_I2;
    float sn2 = sn * sn, inv_sn2 = 1.0f / sn2, c2n = 0.5f * inv_sn2;
    float dI = I2 - I1;
    float I_diff = dI * ERFW_C;
    float I_min  = I1 + 0.5f * dI * (1.0f - ERFW_C);
    float A    = dI * rsqrtf(2.0f * PI_F * sb * sb);
    float beta = 2.0f * A * inv_sn2;
    float nC2  = -c2n * L2E;
    float ln_sn = flog2(sn) * LN2_F;
    float CONST0 = -logf(2.0f * WF * dI) - logf(A) - logf(sn) + 0.5f * LN2_F;

    float rr0 = *w1, rr1 = *w2, rr2 = *w12;
    float rm = fmaxf(rr0, fmaxf(rr1, rr2));
    float lse_r = rm + LN2_F * flog2(fexp2((rr0 - rm) * L2E)
                 + fexp2((rr1 - rm) * L2E) + fexp2((rr2 - rm) * L2E));
    float lw0 = rr0 - lse_r, lw1 = rr1 - lse_r, lw2 = rr2 - lse_r;
    float base12 = flog2(I_diff) * LN2_F - 8.0f * LN2_F;
    float Qc = -ln_sn - 0.5f * LOG2PI_F;
    float K  = LN2_F - flog2(GAMMA_1_5) * LN2_F - 4.0f * ln_sn - 0.5f * LOG2PI_F;

    if (tid < N_MC) {
        // ---- per-n constants (log2 domain): s = Pp + T*x + B*y + nC2*x^2 ----
        float tx = k_u[tid] * I_diff + I_min;
        float u  = 2.0f * (tx - I1) / dI - 1.0f;
        float ei = erfinvf(u);
        float e2 = ei * ei;
        float lptx = -logf(2.0f * WF * dI) + 0.5f * LOG2PI_F + e2;
        float G = A * expf(-e2);
        float b = 2.0f * G / sn2;       // z = b*y
        float P = lptx - 0.5f * logf(G) - 0.5f * logf(b) - G * G / sn2
                - 2.0f * logf(sn) + 0.5f * logf(2.0f / PI_F);
        sPp[tid] = (P - c2n * tx * tx) * L2E;
        sT[tid]  = (tx * inv_sn2) * L2E;
        sB[tid]  = b * L2E;
    } else {
        // ---- per-m record {x, y, D2, Cl2} for mi = tid-256 ----
        int mi = tid - N_MC;
        int m  = mb + mi;
        float4 o;
        if (m < Mv) {
            float xv = x_g[m], yv = y_g[m];
            // analytic upper bound C on max_n (P + b*y): unimodal in g
            float disc = fmaf(yv, yv, -4.0f * sn2);
            float root = sqrtf(fmaxf(disc, 0.0f));
            float gs = (yv + root) / (2.0f * A);
            gs = fminf(fmaxf(gs, GMIN_C), 1.0f);
            float Ag = A * gs;
            float Cnn = CONST0 - 2.0f * flog2(gs) * LN2_F - Ag * Ag * inv_sn2
                      + beta * gs * yv;
            float Cl2 = fmaf(Cnn, L2E, 2.0f);         // +2 bits safety margin
            float D2  = fmaf(nC2 * xv, xv, -Cl2);     // nC2*x^2 - C
            o = make_float4(xv, yv, D2, Cl2);
        } else {
            o = make_float4(0.5f, 0.5f, -20000.0f, 0.0f);
        }
        srec[mi] = o;
    }
    __syncthreads();

    // ---- each thread: 4 m's from LDS, packed as 2 x float2 ----
    float4 r0v = srec[lane];
    float4 r1v = srec[64 + lane];
    float4 r2v = srec[128 + lane];
    float4 r3v = srec[192 + lane];
    v2f x01 = {r0v.x, r1v.x}, y01 = {r0v.y, r1v.y}, d01 = {r0v.z, r1v.z};
    v2f x23 = {r2v.x, r3v.x}, y23 = {r2v.y, r3v.y}, d23 = {r2v.z, r3v.z};

    const float4* P4 = (const float4*)sPp;
    const float4* T4 = (const float4*)sT;
    const float4* B4 = (const float4*)sB;
    int g0 = wv * (NSLICE / 4);

    v2f a01 = {0.0f, 0.0f}, a23 = {0.0f, 0.0f};
#pragma unroll 2
    for (int g = 0; g < NSLICE / 4; ++g) {
        float4 P = P4[g0 + g];
        float4 T = T4[g0 + g];
        float4 B = B4[g0 + g];
        PAIRV(P.x, T.x, B.x)
        PAIRV(P.y, T.y, B.y)
        PAIRV(P.z, T.z, B.z)
        PAIRV(P.w, T.w, B.w)
    }

    part[wv][lane]       = a01.x;
    part[wv][lane + 64]  = a01.y;
    part[wv][lane + 128] = a23.x;
    part[wv][lane + 192] = a23.y;
    __syncthreads();

    // ---- epilogue: mixture LSE per m (threads 0..255), wave butterfly ----
    if (tid < MPB) {
        int mi = tid;
        float sm = 0.0f;
#pragma unroll
        for (int w = 0; w < 8; ++w) sm += part[w][mi];
        float4 rr = srec[mi];
        double lpd = 0.0;
        if (mb + mi < Mv) {
            float xv = rr.x, yv = rr.y, Cl2 = rr.w;
            float ly  = flog2(yv) * LN2_F;
            float y2s = yv * yv * inv_sn2;
            float lp12 = base12 + ly - y2s + Qc + LN2_F * (Cl2 + flog2(sm));
            float e1 = xv - I1, e2v = xv - I2;
            float base_i = K + 2.0f * ly - y2s;
            float lp1 = base_i - c2n * e1 * e1;
            float lp2 = base_i - c2n * e2v * e2v;
            float b0 = lw0 + lp1, b1 = lw1 + lp2, b2 = lw2 + lp12;
            float mm = fmaxf(b0, fmaxf(b1, b2));
            float lp = mm + LN2_F * flog2(fexp2((b0 - mm) * L2E)
                      + fexp2((b1 - mm) * L2E) + fexp2((b2 - mm) * L2E));
            lpd = (double)lp;
        }
#pragma unroll
        for (int o = 32; o > 0; o >>= 1) lpd += __shfl_xor(lpd, o, 64);
        if (lane == 0) sred[wv] = lpd;
    }
    __syncthreads();
    if (tid == 0) partials[blockIdx.x] = (sred[0] + sred[1]) + (sred[2] + sred[3]);
}

// ---------------- final reduction ----------------
__global__ void reduce_kernel(const double* __restrict__ partials, float* __restrict__ out) {
    __shared__ double red[256];
    double a = 0.0;
    for (int i = threadIdx.x; i < MAIN_BLOCKS; i += 256) a += partials[i];
    red[threadIdx.x] = a;
    __syncthreads();
    for (int s = 128; s > 0; s >>= 1) {
        if (threadIdx.x < s) red[threadIdx.x] += red[threadIdx.x + s];
        __syncthreads();
    }
    if (threadIdx.x == 0) out[0] = (float)(-red[0]);
}

extern "C" void kernel_launch(void* const* d_in, const int* in_sizes, int n_in,
                              void* d_out, int out_size, void* d_ws, size_t ws_size,
                              hipStream_t stream) {
    const float* x   = (const float*)d_in[0];
    const float* y   = (const float*)d_in[1];
    const float* k_u = (const float*)d_in[2];
    const float* sb  = (const float*)d_in[3];
    const float* sn  = (const float*)d_in[4];
    const float* I1  = (const float*)d_in[5];
    const float* I2  = (const float*)d_in[6];
    const float* w1  = (const float*)d_in[7];
    const float* w2  = (const float*)d_in[8];
    const float* w12 = (const float*)d_in[9];
    int Mv = in_sizes[0];

    double* partials = (double*)d_ws;   // always fully written; no init needed

    fused_kernel<<<MAIN_BLOCKS, CB, 0, stream>>>(x, y, k_u, sb, sn, I1, I2,
                                                 w1, w2, w12, partials, Mv);
    reduce_kernel<<<1, 256, 0, stream>>>(partials, (float*)d_out);
}